// Round 17
// baseline (7753.561 us; speedup 1.0000x reference)
//
#include <hip/hip_runtime.h>
#include <hip/hip_bf16.h>

#define BB 32
#define TD 800
#define TO 400
#define AA 256
#define EE 512
#define VV 8192
#define G4 1024
#define MM (BB*TO)        // 12800
#define TP 896            // padded Td for fp32 kT (16B-aligned slice starts)
#define NEGI -3.4e38f

typedef __attribute__((ext_vector_type(8))) short bf16x8;
typedef __attribute__((ext_vector_type(4))) float f32x4;

__device__ __forceinline__ float sigm(float x){ return 1.f/(1.f+expf(-x)); }

__device__ __forceinline__ ushort f2bf(float x){
  uint u = __float_as_uint(x);
  u += 0x7fffu + ((u >> 16) & 1u);   // RNE; inputs are finite
  return (ushort)(u >> 16);
}

__device__ __forceinline__ float decode_ptf(const void* p){
  int w = *(const int*)p;
  if (w >= 0 && w < 1048576) return (float)w;
  return __int_as_float(w);
}

// fabric-coherent primitives (no L2 invalidation, no wbl2) — proven R11
__device__ __forceinline__ void ast(float* p, float v){
  __hip_atomic_store(p, v, __ATOMIC_RELAXED, __HIP_MEMORY_SCOPE_AGENT);
}
__device__ __forceinline__ float ald(const float* p){
  return __hip_atomic_load(p, __ATOMIC_RELAXED, __HIP_MEMORY_SCOPE_AGENT);
}
__device__ __forceinline__ void sig(uint* p){
  asm volatile("s_waitcnt vmcnt(0)" ::: "memory");
  __hip_atomic_fetch_add(p, 1u, __ATOMIC_RELAXED, __HIP_MEMORY_SCOPE_AGENT);
}
__device__ __forceinline__ uint poll(uint* p){
  return __hip_atomic_fetch_add(p, 0u, __ATOMIC_RELAXED, __HIP_MEMORY_SCOPE_AGENT);
}

// ---- WF[(r*128+q)*512+k] = Wcat[j(q,r)][k] fp32; WihxT[e][j] fp32
__global__ void kprep_w(const float* __restrict__ Wih, const float* __restrict__ Whh,
                        float* __restrict__ WF, float* __restrict__ WihxT){
  int id = blockIdx.x*blockDim.x + threadIdx.x;
  const int total = 8*128*512 + EE*G4;
  for (; id < total; id += gridDim.x*blockDim.x){
    if (id < 8*128*512){
      int kk = id & 511; int rq = id >> 9; int q = rq & 127; int r = rq >> 7;
      int j = ((q>>5)<<8) + (r<<5) + (q&31);
      WF[id] = (kk < AA) ? Wih[j*768 + EE + kk] : Whh[j*AA + (kk-AA)];
    } else {
      int i2 = id - 8*128*512;
      int e = i2 >> 10, j = i2 & 1023;
      WihxT[i2] = Wih[j*768 + e];
    }
  }
}

// ---- kT[b][a][t] fp32, t zero-padded to 896
__global__ void kprep_kT(const float* __restrict__ k, float* __restrict__ kT){
  int id = blockIdx.x*blockDim.x + threadIdx.x;
  const int nk = BB*AA*TP;
  for (; id < nk; id += gridDim.x*blockDim.x){
    int t = id % TP;
    int rest = id / TP;
    int a = rest & (AA-1);
    int b = rest >> 8;
    kT[id] = (t < TD) ? k[((size_t)b*TD + t)*AA + a] : 0.f;
  }
}

// ---- XG8[((m*8)+r)*128 + g*32 + a_local] = fp32 gate bias (incl b_ih+b_hh)
__global__ __launch_bounds__(256) void kxg(const int* __restrict__ gt,
                     const float* __restrict__ embW,
                     const float* __restrict__ WihxT, const float* __restrict__ bih,
                     const float* __restrict__ bhh, float* __restrict__ XG8){
  __shared__ float Xs[16][64];
  __shared__ int toks[16];
  const int m0 = blockIdx.x * 16;
  const int j0 = blockIdx.y * 256 + (threadIdx.x & 63)*4;
  const int r0 = (threadIdx.x >> 6) * 4;
  float acc[4][4];
  #pragma unroll
  for (int rr=0;rr<4;++rr){ acc[rr][0]=acc[rr][1]=acc[rr][2]=acc[rr][3]=0.f; }
  if (threadIdx.x < 16) toks[threadIdx.x] = gt[m0 + threadIdx.x];
  __syncthreads();
  for (int kc=0; kc<EE; kc+=64){
    {
      int lr = threadIdx.x >> 4;
      int lq = threadIdx.x & 15;
      const float4 xv = *(const float4*)(embW + (size_t)toks[lr]*EE + kc + lq*4);
      Xs[lr][lq*4+0]=xv.x; Xs[lr][lq*4+1]=xv.y; Xs[lr][lq*4+2]=xv.z; Xs[lr][lq*4+3]=xv.w;
    }
    __syncthreads();
    #pragma unroll 4
    for (int kk=0; kk<64; ++kk){
      const float4 wv = *(const float4*)(WihxT + (size_t)(kc+kk)*G4 + j0);
      #pragma unroll
      for (int rr=0;rr<4;++rr){
        float xs = Xs[r0+rr][kk];
        acc[rr][0] += wv.x*xs; acc[rr][1] += wv.y*xs;
        acc[rr][2] += wv.z*xs; acc[rr][3] += wv.w*xs;
      }
    }
    __syncthreads();
  }
  const float4 b1 = *(const float4*)(bih + j0);
  const float4 b2 = *(const float4*)(bhh + j0);
  const int g  = j0 >> 8;
  const int rr8 = (j0 >> 5) & 7;
  const int al = j0 & 31;
  #pragma unroll
  for (int rr=0;rr<4;++rr){
    float4 o4 = make_float4(acc[rr][0]+b1.x+b2.x, acc[rr][1]+b1.y+b2.y,
                            acc[rr][2]+b1.z+b2.z, acc[rr][3]+b1.w+b2.w);
    int m = m0 + r0 + rr;
    *(float4*)(XG8 + ((size_t)m*8 + rr8)*128 + g*32 + al) = o4;
  }
}

// ---- 8-block-per-batch clustered recurrence (R11 protocol)
//      + h-half of gate GEMV precomputed in barrier-B poll shadow (bit-exact split)
__global__ __launch_bounds__(1024) void kseq8(
    const float* __restrict__ kT, const float* __restrict__ v,
    const int* __restrict__ enc, const void* __restrict__ ptfp,
    const float* __restrict__ WF, const float* __restrict__ embW,
    const float* __restrict__ charb, const float* __restrict__ u,
    const float* __restrict__ XG8, const float* __restrict__ WihxT,
    const float* __restrict__ bih, const float* __restrict__ bhh,
    float* __restrict__ HC, float* __restrict__ Hx, float* __restrict__ Ex,
    uint* __restrict__ cnt)
{
  __shared__ float kTl[256*128];   // 128KB: my t-slice of kT, [a][tl]
  __shared__ float s_hc[EE];       // ctx(0..255) || h(256..511)
  __shared__ float part[8*128];    // energy partials / ctx-quarter gate partials
  __shared__ float gpart_h[4*128]; // h-quarter gate partials (shadow-computed)
  __shared__ float cpart[4*256];
  __shared__ float e_s[128];
  __shared__ float c_s[32];
  __shared__ float red[16];
  __shared__ float wr_s[8];
  __shared__ float Ssum;
  __shared__ float x_s[512];
  __shared__ float xq_s[128];
  __shared__ float rv[16];
  __shared__ int   ri[16];
  __shared__ int   pred_s;

  const int blk = blockIdx.x;
  const int r = blk & 7;           // rank -> XCD under round-robin (perf heuristic only)
  const int b = blk >> 3;
  const int tid = threadIdx.x;
  const int len = enc[b];
  const int c4 = (((len + 7) >> 3) + 3) & ~3;   // 16B-aligned slice width, <=104
  const int t0 = r*c4;
  const int t1 = min(t0 + c4, len);
  const int tn = max(0, t1 - t0);
  const float ptf = decode_ptf(ptfp);
  uint* mycnt = cnt + b*32;

  for (int i = tid; i < 256*32; i += 1024){
    int a = i >> 5, q4 = i & 31;
    float4 x = *(const float4*)(kT + ((size_t)b*AA + a)*TP + t0 + q4*4);
    *(float4*)(&kTl[a*128 + q4*4]) = x;
  }
  if (tid < 512) s_hc[tid] = 0.f;
  if (tid < 512) gpart_h[tid & 511] = 0.f;   // == W_h · h0(=0), bit-identical to +0.0 sums
  if (tid < 32)  c_s[tid] = 0.f;
  if (tid == 0)  pred_s = 0;
  __syncthreads();

  uint bar_target = 0;

  for (int t=0; t<TO; ++t){
    const int m = b*TO + t;
    const bool tf = (u[t] < ptf);

    float xg0=0.f, xg1=0.f, xg2=0.f, xg3=0.f;
    if (tf){
      if (tid < 32){
        const float* xb = XG8 + ((size_t)m*8 + r)*128;
        xg0 = xb[tid]; xg1 = xb[32+tid]; xg2 = xb[64+tid]; xg3 = xb[96+tid];
      }
    } else {
      for (int i=tid; i<512; i+=1024) x_s[i] = embW[(size_t)pred_s*EE + i];
      __syncthreads();
      if (tid < 128){
        int q = tid;
        int j = ((q>>5)<<8) + (r<<5) + (q&31);
        float a0 = bih[j] + bhh[j];
        for (int e=0;e<EE;++e) a0 += x_s[e]*WihxT[(size_t)e*G4 + j];
        xq_s[q] = a0;
      }
      __syncthreads();
    }

    // ---- gates ctx-quarters (kq 0..3); h-quarters already in gpart_h (shadow)
    if (tid < 512){
      const int q = tid & 127, kq = tid >> 7;    // kq 0..3
      const float4* wp = (const float4*)(WF + ((size_t)r*128 + q)*512) + kq*16;
      const float* sp = s_hc + kq*64;
      float ac0=0.f, ac1=0.f, ac2=0.f, ac3=0.f;
      #pragma unroll
      for (int i=0;i<8;++i){
        float4 w0 = wp[2*i], w1 = wp[2*i+1];
        float s0=sp[8*i+0], s1=sp[8*i+1], s2=sp[8*i+2], s3=sp[8*i+3];
        float s4=sp[8*i+4], s5=sp[8*i+5], s6=sp[8*i+6], s7=sp[8*i+7];
        ac0 = fmaf(w0.x,s0,ac0); ac1 = fmaf(w0.y,s1,ac1);
        ac2 = fmaf(w0.z,s2,ac2); ac3 = fmaf(w0.w,s3,ac3);
        ac0 = fmaf(w1.x,s4,ac0); ac1 = fmaf(w1.y,s5,ac1);
        ac2 = fmaf(w1.z,s6,ac2); ac3 = fmaf(w1.w,s7,ac3);
      }
      part[kq*128 + q] = (ac0+ac1)+(ac2+ac3);
    }
    __syncthreads();

    // ---- LSTM pointwise (local 32-wide a-slice); sum quarters in original 0..7 order
    if (tid < 32){
      float gi, gf, gg, go;
      if (tf){ gi=xg0; gf=xg1; gg=xg2; go=xg3; }
      else   { gi=xq_s[tid]; gf=xq_s[32+tid]; gg=xq_s[64+tid]; go=xq_s[96+tid]; }
      #pragma unroll
      for (int kq=0;kq<4;++kq){
        const float* pp = part + kq*128;
        gi += pp[tid]; gf += pp[32+tid]; gg += pp[64+tid]; go += pp[96+tid];
      }
      #pragma unroll
      for (int kq=0;kq<4;++kq){
        const float* pp = gpart_h + kq*128;
        gi += pp[tid]; gf += pp[32+tid]; gg += pp[64+tid]; go += pp[96+tid];
      }
      float cn = sigm(gf)*c_s[tid] + sigm(gi)*tanhf(gg);
      float hn = sigm(go)*tanhf(cn);
      c_s[tid] = cn;
      HC[(size_t)m*EE + r*32 + tid] = hn;
      ast(Hx + b*256 + r*32 + tid, hn);
    }
    // ---- barrier A (h published)
    bar_target += 8;
    __syncthreads();
    if (tid == 0){
      sig(mycnt);
      while (poll(mycnt) < bar_target) __builtin_amdgcn_s_sleep(1);
    }
    __syncthreads();

    if (tid < 256) s_hc[256 + tid] = ald(Hx + b*256 + tid);
    __syncthreads();

    // ---- energy partials from LDS kT slice
    {
      const int tq = tid & 127, aq = tid >> 7;
      const float* kp = kTl + (aq*32)*128 + tq;
      const float* hp = s_hc + 256 + aq*32;
      float ac0=0.f, ac1=0.f, ac2=0.f, ac3=0.f;
      #pragma unroll
      for (int i=0;i<8;++i){
        float k0 = kp[(4*i+0)*128], h0 = hp[4*i+0];
        float k1 = kp[(4*i+1)*128], h1 = hp[4*i+1];
        float k2 = kp[(4*i+2)*128], h2 = hp[4*i+2];
        float k3 = kp[(4*i+3)*128], h3 = hp[4*i+3];
        ac0 = fmaf(k0,h0,ac0); ac1 = fmaf(k1,h1,ac1);
        ac2 = fmaf(k2,h2,ac2); ac3 = fmaf(k3,h3,ac3);
      }
      part[aq*128 + tq] = (ac0+ac1)+(ac2+ac3);
    }
    __syncthreads();

    if (tid < 128){
      float ev = NEGI;
      if (tid < tn){
        ev = 0.f;
        #pragma unroll
        for (int q=0;q<8;++q) ev += part[q*128 + tid];
      }
      e_s[tid] = ev;
    }
    __syncthreads();
    if (tid < 64){
      float a = fmaxf(e_s[tid], e_s[64+tid]);
      #pragma unroll
      for (int o=1;o<64;o<<=1) a = fmaxf(a, __shfl_xor(a,o));
      if (tid == 0) red[0] = a;
    }
    __syncthreads();
    const float m_i = red[0];
    if (tid < 128) e_s[tid] = expf(e_s[tid] - m_i);
    __syncthreads();
    if (tid < 64){
      float a = e_s[tid] + e_s[64+tid];
      #pragma unroll
      for (int o=1;o<64;o<<=1) a += __shfl_xor(a,o);
      if (tid == 0) red[1] = a;
    }
    __syncthreads();

    // ---- ctx partials over my t-slice: p × v (warm L2, natural layout)
    {
      const int a = tid & 255, g = tid >> 8;
      float acc = 0.f;
      for (int tt = g; tt < tn; tt += 4){
        acc = fmaf(e_s[tt], v[((size_t)b*TD + t0 + tt)*AA + a], acc);
      }
      cpart[g*256 + a] = acc;
    }
    __syncthreads();
    {
      float* exr = Ex + ((size_t)b*8 + r)*260;
      if (tid < 256){
        float cp = cpart[tid] + cpart[256+tid] + cpart[512+tid] + cpart[768+tid];
        ast(exr + 2 + tid, cp);
      }
      if (tid == 0){ ast(exr + 0, m_i); ast(exr + 1, red[1]); }
    }
    // ---- barrier B (partials published); h-quarter gate GEMV for next step
    //      runs in the poll shadow (threads 512..1023; s_hc[256..]=h(t) is stable)
    bar_target += 8;
    __syncthreads();
    if (tid == 0){
      sig(mycnt);
      while (poll(mycnt) < bar_target) __builtin_amdgcn_s_sleep(1);
    } else if (tid >= 512){
      const int q = tid & 127, kqh = (tid >> 7) - 4;   // 0..3 -> quarters 4..7
      const float4* wp = (const float4*)(WF + ((size_t)r*128 + q)*512) + (kqh+4)*16;
      const float* sp = s_hc + 256 + kqh*64;
      float ac0=0.f, ac1=0.f, ac2=0.f, ac3=0.f;
      #pragma unroll
      for (int i=0;i<8;++i){
        float4 w0 = wp[2*i], w1 = wp[2*i+1];
        float s0=sp[8*i+0], s1=sp[8*i+1], s2=sp[8*i+2], s3=sp[8*i+3];
        float s4=sp[8*i+4], s5=sp[8*i+5], s6=sp[8*i+6], s7=sp[8*i+7];
        ac0 = fmaf(w0.x,s0,ac0); ac1 = fmaf(w0.y,s1,ac1);
        ac2 = fmaf(w0.z,s2,ac2); ac3 = fmaf(w0.w,s3,ac3);
        ac0 = fmaf(w1.x,s4,ac0); ac1 = fmaf(w1.y,s5,ac1);
        ac2 = fmaf(w1.z,s6,ac2); ac3 = fmaf(w1.w,s7,ac3);
      }
      gpart_h[kqh*128 + q] = (ac0+ac1)+(ac2+ac3);
    }
    __syncthreads();

    // ---- combine (fresh pipelined fabric loads; identical fp32 math in every block)
    if (tid < 16){
      int i = tid & 7;
      red[tid] = ald(Ex + ((size_t)b*8 + i)*260 + (tid >> 3));
    }
    __syncthreads();
    if (tid == 0){
      float M = red[0];
      #pragma unroll
      for (int i=1;i<8;++i) M = fmaxf(M, red[i]);
      float S = 0.f;
      #pragma unroll
      for (int i=0;i<8;++i){
        float w = expf(red[i] - M);
        wr_s[i] = w;
        S += w * red[8+i];
      }
      Ssum = S;
    }
    __syncthreads();
    if (tid < 256){
      float* exb = Ex + (size_t)b*8*260 + 2 + tid;
      float c0 = ald(exb + 0*260), c1 = ald(exb + 1*260);
      float c2 = ald(exb + 2*260), c3 = ald(exb + 3*260);
      float c4v= ald(exb + 4*260), c5 = ald(exb + 5*260);
      float c6 = ald(exb + 6*260), c7 = ald(exb + 7*260);
      float cc = wr_s[0]*c0 + wr_s[1]*c1 + wr_s[2]*c2 + wr_s[3]*c3
               + wr_s[4]*c4v + wr_s[5]*c5 + wr_s[6]*c6 + wr_s[7]*c7;
      float cv = cc / Ssum;
      s_hc[tid] = cv;
      if ((tid >> 5) == r) HC[(size_t)m*EE + 256 + tid] = cv;
    }
    __syncthreads();

    const bool need_pred = (t+1 < TO) && !(u[t+1] < ptf);
    if (need_pred){
      const int lane = tid & 63, wvi = tid >> 6;
      float bvv = -3.4e38f; int bii = 0;
      for (int rr=0; rr<8; ++rr){
        int vg = tid*8 + rr;
        float a2 = charb[vg];
        const float* er = embW + (size_t)vg*EE;
        for (int e=0;e<AA;++e) a2 += er[e]*s_hc[256+e];
        for (int e=0;e<AA;++e) a2 += er[AA+e]*s_hc[e];
        if (a2 > bvv){ bvv=a2; bii=vg; }
      }
      #pragma unroll
      for (int o=1;o<64;o<<=1){
        float ov = __shfl_xor(bvv,o); int oi = __shfl_xor(bii,o);
        if (ov > bvv || (ov == bvv && oi < bii)){ bvv=ov; bii=oi; }
      }
      if (lane==0){ rv[wvi]=bvv; ri[wvi]=bii; }
      __syncthreads();
      if (tid==0){
        float fv=rv[0]; int fi=ri[0];
        for (int w2=1;w2<16;++w2){
          if (rv[w2]>fv || (rv[w2]==fv && ri[w2]<fi)){ fv=rv[w2]; fi=ri[w2]; }
        }
        pred_s = fi;
      }
      __syncthreads();
      // recompute h-quarters with (possibly) new pred path state? not needed:
      // gpart_h depends only on h(t), unchanged by pred. nothing to do.
    }
  }
}

// ---- convert HC and embW to bf16 (row-major, K contiguous)
__global__ void kcvt(const float* __restrict__ HC, const float* __restrict__ embW,
                     ushort* __restrict__ HCb, ushort* __restrict__ embB){
  int id = blockIdx.x*blockDim.x + threadIdx.x;
  const int n1 = MM*EE;        // HC elems
  const int n2 = VV*EE;        // emb elems
  for (; id < n1 + n2; id += gridDim.x*blockDim.x){
    if (id < n1){
      HCb[id] = f2bf(HC[id]);
    } else {
      int i2 = id - n1;
      embB[i2] = f2bf(embW[i2]);
    }
  }
}

// ---- logits via MFMA: D[v][m] = emb[v][:]·HC[m][:]; out fp32 (B,V,To)
__global__ __launch_bounds__(256) void klogits_mfma(
    const ushort* __restrict__ HCb, const ushort* __restrict__ embB,
    const float* __restrict__ charb, float* __restrict__ out)
{
  const int mb = blockIdx.x;          // 0..199
  const int vb = blockIdx.y;          // 0..127
  const int wid = threadIdx.x >> 6;
  const int lane = threadIdx.x & 63;
  const int lrow = lane & 15;
  const int lk   = (lane >> 4) * 8;   // k-chunk 0/8/16/24
  const int v0 = vb*64 + wid*16;
  const int m0 = mb*64;

  f32x4 acc0 = {0.f,0.f,0.f,0.f}, acc1 = {0.f,0.f,0.f,0.f};
  f32x4 acc2 = {0.f,0.f,0.f,0.f}, acc3 = {0.f,0.f,0.f,0.f};

  const ushort* ea = embB + (size_t)(v0 + lrow)*EE + lk;
  const ushort* h0 = HCb + (size_t)(m0 +      lrow)*EE + lk;
  const ushort* h1 = HCb + (size_t)(m0 + 16 + lrow)*EE + lk;
  const ushort* h2 = HCb + (size_t)(m0 + 32 + lrow)*EE + lk;
  const ushort* h3 = HCb + (size_t)(m0 + 48 + lrow)*EE + lk;

  #pragma unroll 4
  for (int kc = 0; kc < EE; kc += 32){
    bf16x8 a  = *(const bf16x8*)(ea + kc);
    bf16x8 b0 = *(const bf16x8*)(h0 + kc);
    bf16x8 b1 = *(const bf16x8*)(h1 + kc);
    bf16x8 b2 = *(const bf16x8*)(h2 + kc);
    bf16x8 b3 = *(const bf16x8*)(h3 + kc);
    acc0 = __builtin_amdgcn_mfma_f32_16x16x32_bf16(a, b0, acc0, 0,0,0);
    acc1 = __builtin_amdgcn_mfma_f32_16x16x32_bf16(a, b1, acc1, 0,0,0);
    acc2 = __builtin_amdgcn_mfma_f32_16x16x32_bf16(a, b2, acc2, 0,0,0);
    acc3 = __builtin_amdgcn_mfma_f32_16x16x32_bf16(a, b3, acc3, 0,0,0);
  }

  // D layout: col(m_local)=lane&15, row(v_local)=(lane>>4)*4+reg
  const int vbase = v0 + (lane >> 4)*4;
  #pragma unroll
  for (int j=0; j<4; ++j){
    const f32x4 av = (j==0)?acc0:(j==1)?acc1:(j==2)?acc2:acc3;
    const int m = m0 + j*16 + (lane & 15);
    const int bb = m / TO;
    const int tt = m - bb*TO;
    float* op = out + (size_t)bb*VV*TO + tt;
    #pragma unroll
    for (int i=0;i<4;++i){
      int vg = vbase + i;
      op[(size_t)vg*TO] = av[i] + charb[vg];
    }
  }
}

extern "C" void kernel_launch(void* const* d_in, const int* in_sizes, int n_in,
                              void* d_out, int out_size, void* d_ws, size_t ws_size,
                              hipStream_t stream)
{
  const float* k    = (const float*)d_in[0];
  const float* v    = (const float*)d_in[1];
  const int*   enc  = (const int*)d_in[2];
  const int*   gt   = (const int*)d_in[3];
  const void*  ptf  = d_in[4];
  const float* embW = (const float*)d_in[5];
  const float* Wih  = (const float*)d_in[6];
  const float* Whh  = (const float*)d_in[7];
  const float* bih  = (const float*)d_in[8];
  const float* bhh  = (const float*)d_in[9];
  const float* chb  = (const float*)d_in[10];
  const float* u    = (const float*)d_in[11];
  float* out = (float*)d_out;

  float* ws   = (float*)d_ws;
  uint*  cnt  = (uint*)ws;                        // 1024 u
  float* Hx   = ws + 1024;                        // 32*256
  float* Ex   = Hx + (size_t)BB*256;              // 32*8*260
  float* XG8  = Ex + (size_t)BB*8*260;            // 12800*1024 f (52.4MB)
  float* HC   = XG8 + (size_t)MM*G4;              // 12800*512 f (26.2MB)
  float* WihxT= HC  + (size_t)MM*EE;              // 512*1024 f
  float* WF   = WihxT + (size_t)EE*G4;            // 8*128*512 f (2.1MB)
  float* kT   = WF + (size_t)8*128*512;           // 32*256*896 f (29.4MB)
  ushort* HCb = (ushort*)XG8;                     // aliases XG8 (dead after kseq8): 13.1MB
  ushort* embB= HCb + (size_t)MM*EE;              // +8.4MB (still inside XG8's 52MB)

  hipMemsetAsync(cnt, 0, 1024*sizeof(uint), stream);
  kprep_w  <<<1024, 256, 0, stream>>>(Wih, Whh, WF, WihxT);
  kprep_kT <<<8192, 256, 0, stream>>>(k, kT);
  kxg      <<<dim3(800,4), 256, 0, stream>>>(gt, embW, WihxT, bih, bhh, XG8);
  kseq8    <<<256, 1024, 0, stream>>>(kT, v, enc, ptf, WF, embW, chb, u,
                                      XG8, WihxT, bih, bhh, HC, Hx, Ex, cnt);
  kcvt     <<<4096, 256, 0, stream>>>(HC, embW, HCb, embB);
  klogits_mfma <<<dim3(200,128), 256, 0, stream>>>(HCb, embB, chb, out);
}

// Round 18
// 6406.757 us; speedup vs baseline: 1.2102x; 1.2102x over previous
//
#include <hip/hip_runtime.h>
#include <hip/hip_bf16.h>

#define BB 32
#define TD 800
#define TO 400
#define AA 256
#define EE 512
#define VV 8192
#define G4 1024
#define MM (BB*TO)        // 12800
#define TP 896            // padded Td for fp32 kT (16B-aligned slice starts)
#define NEGI -3.4e38f

typedef __attribute__((ext_vector_type(8))) short bf16x8;
typedef __attribute__((ext_vector_type(4))) float f32x4;

__device__ __forceinline__ float sigm(float x){ return 1.f/(1.f+expf(-x)); }

__device__ __forceinline__ ushort f2bf(float x){
  uint u = __float_as_uint(x);
  u += 0x7fffu + ((u >> 16) & 1u);   // RNE; inputs are finite
  return (ushort)(u >> 16);
}

__device__ __forceinline__ float decode_ptf(const void* p){
  int w = *(const int*)p;
  if (w >= 0 && w < 1048576) return (float)w;
  return __int_as_float(w);
}

// fabric-coherent primitives (no L2 invalidation, no wbl2) — proven R11
__device__ __forceinline__ void ast(float* p, float v){
  __hip_atomic_store(p, v, __ATOMIC_RELAXED, __HIP_MEMORY_SCOPE_AGENT);
}
__device__ __forceinline__ float ald(const float* p){
  return __hip_atomic_load(p, __ATOMIC_RELAXED, __HIP_MEMORY_SCOPE_AGENT);
}
__device__ __forceinline__ void sig(uint* p){
  asm volatile("s_waitcnt vmcnt(0)" ::: "memory");
  __hip_atomic_fetch_add(p, 1u, __ATOMIC_RELAXED, __HIP_MEMORY_SCOPE_AGENT);
}
__device__ __forceinline__ uint poll(uint* p){
  return __hip_atomic_fetch_add(p, 0u, __ATOMIC_RELAXED, __HIP_MEMORY_SCOPE_AGENT);
}

// ---- WF[(r*128+q)*512+k] = Wcat[j(q,r)][k] fp32; WihxT[e][j] fp32
__global__ void kprep_w(const float* __restrict__ Wih, const float* __restrict__ Whh,
                        float* __restrict__ WF, float* __restrict__ WihxT){
  int id = blockIdx.x*blockDim.x + threadIdx.x;
  const int total = 8*128*512 + EE*G4;
  for (; id < total; id += gridDim.x*blockDim.x){
    if (id < 8*128*512){
      int kk = id & 511; int rq = id >> 9; int q = rq & 127; int r = rq >> 7;
      int j = ((q>>5)<<8) + (r<<5) + (q&31);
      WF[id] = (kk < AA) ? Wih[j*768 + EE + kk] : Whh[j*AA + (kk-AA)];
    } else {
      int i2 = id - 8*128*512;
      int e = i2 >> 10, j = i2 & 1023;
      WihxT[i2] = Wih[j*768 + e];
    }
  }
}

// ---- kT[b][a][t] fp32, t zero-padded to 896
__global__ void kprep_kT(const float* __restrict__ k, float* __restrict__ kT){
  int id = blockIdx.x*blockDim.x + threadIdx.x;
  const int nk = BB*AA*TP;
  for (; id < nk; id += gridDim.x*blockDim.x){
    int t = id % TP;
    int rest = id / TP;
    int a = rest & (AA-1);
    int b = rest >> 8;
    kT[id] = (t < TD) ? k[((size_t)b*TD + t)*AA + a] : 0.f;
  }
}

// ---- XG8[((m*8)+r)*128 + g*32 + a_local] = fp32 gate bias (incl b_ih+b_hh)
__global__ __launch_bounds__(256) void kxg(const int* __restrict__ gt,
                     const float* __restrict__ embW,
                     const float* __restrict__ WihxT, const float* __restrict__ bih,
                     const float* __restrict__ bhh, float* __restrict__ XG8){
  __shared__ float Xs[16][64];
  __shared__ int toks[16];
  const int m0 = blockIdx.x * 16;
  const int j0 = blockIdx.y * 256 + (threadIdx.x & 63)*4;
  const int r0 = (threadIdx.x >> 6) * 4;
  float acc[4][4];
  #pragma unroll
  for (int rr=0;rr<4;++rr){ acc[rr][0]=acc[rr][1]=acc[rr][2]=acc[rr][3]=0.f; }
  if (threadIdx.x < 16) toks[threadIdx.x] = gt[m0 + threadIdx.x];
  __syncthreads();
  for (int kc=0; kc<EE; kc+=64){
    {
      int lr = threadIdx.x >> 4;
      int lq = threadIdx.x & 15;
      const float4 xv = *(const float4*)(embW + (size_t)toks[lr]*EE + kc + lq*4);
      Xs[lr][lq*4+0]=xv.x; Xs[lr][lq*4+1]=xv.y; Xs[lr][lq*4+2]=xv.z; Xs[lr][lq*4+3]=xv.w;
    }
    __syncthreads();
    #pragma unroll 4
    for (int kk=0; kk<64; ++kk){
      const float4 wv = *(const float4*)(WihxT + (size_t)(kc+kk)*G4 + j0);
      #pragma unroll
      for (int rr=0;rr<4;++rr){
        float xs = Xs[r0+rr][kk];
        acc[rr][0] += wv.x*xs; acc[rr][1] += wv.y*xs;
        acc[rr][2] += wv.z*xs; acc[rr][3] += wv.w*xs;
      }
    }
    __syncthreads();
  }
  const float4 b1 = *(const float4*)(bih + j0);
  const float4 b2 = *(const float4*)(bhh + j0);
  const int g  = j0 >> 8;
  const int rr8 = (j0 >> 5) & 7;
  const int al = j0 & 31;
  #pragma unroll
  for (int rr=0;rr<4;++rr){
    float4 o4 = make_float4(acc[rr][0]+b1.x+b2.x, acc[rr][1]+b1.y+b2.y,
                            acc[rr][2]+b1.z+b2.z, acc[rr][3]+b1.w+b2.w);
    int m = m0 + r0 + rr;
    *(float4*)(XG8 + ((size_t)m*8 + rr8)*128 + g*32 + al) = o4;
  }
}

// ---- 8-block-per-batch clustered recurrence (R11/R13 proven state)
__global__ __launch_bounds__(1024) void kseq8(
    const float* __restrict__ kT, const float* __restrict__ v,
    const int* __restrict__ enc, const void* __restrict__ ptfp,
    const float* __restrict__ WF, const float* __restrict__ embW,
    const float* __restrict__ charb, const float* __restrict__ u,
    const float* __restrict__ XG8, const float* __restrict__ WihxT,
    const float* __restrict__ bih, const float* __restrict__ bhh,
    float* __restrict__ HC, float* __restrict__ Hx, float* __restrict__ Ex,
    uint* __restrict__ cnt)
{
  __shared__ float kTl[256*128];   // 128KB: my t-slice of kT, [a][tl]
  __shared__ float s_hc[EE];       // ctx(0..255) || h(256..511)
  __shared__ float part[8*128];
  __shared__ float cpart[4*256];
  __shared__ float e_s[128];
  __shared__ float c_s[32];
  __shared__ float red[16];
  __shared__ float wr_s[8];
  __shared__ float Ssum;
  __shared__ float x_s[512];
  __shared__ float xq_s[128];
  __shared__ float rv[16];
  __shared__ int   ri[16];
  __shared__ int   pred_s;

  const int blk = blockIdx.x;
  const int r = blk & 7;           // rank -> XCD under round-robin (perf heuristic only)
  const int b = blk >> 3;
  const int tid = threadIdx.x;
  const int len = enc[b];
  const int c4 = (((len + 7) >> 3) + 3) & ~3;   // 16B-aligned slice width, <=104
  const int t0 = r*c4;
  const int t1 = min(t0 + c4, len);
  const int tn = max(0, t1 - t0);
  const float ptf = decode_ptf(ptfp);
  uint* mycnt = cnt + b*32;

  for (int i = tid; i < 256*32; i += 1024){
    int a = i >> 5, q4 = i & 31;
    float4 x = *(const float4*)(kT + ((size_t)b*AA + a)*TP + t0 + q4*4);
    *(float4*)(&kTl[a*128 + q4*4]) = x;
  }
  if (tid < 512) s_hc[tid] = 0.f;
  if (tid < 32)  c_s[tid] = 0.f;
  if (tid == 0)  pred_s = 0;
  __syncthreads();

  uint bar_target = 0;

  for (int t=0; t<TO; ++t){
    const int m = b*TO + t;
    const bool tf = (u[t] < ptf);

    float xg0=0.f, xg1=0.f, xg2=0.f, xg3=0.f;
    if (tf){
      if (tid < 32){
        const float* xb = XG8 + ((size_t)m*8 + r)*128;
        xg0 = xb[tid]; xg1 = xb[32+tid]; xg2 = xb[64+tid]; xg3 = xb[96+tid];
      }
    } else {
      for (int i=tid; i<512; i+=1024) x_s[i] = embW[(size_t)pred_s*EE + i];
      __syncthreads();
      if (tid < 128){
        int q = tid;
        int j = ((q>>5)<<8) + (r<<5) + (q&31);
        float a0 = bih[j] + bhh[j];
        for (int e=0;e<EE;++e) a0 += x_s[e]*WihxT[(size_t)e*G4 + j];
        xq_s[q] = a0;
      }
      __syncthreads();
    }

    // ---- gates partials: fp32 W slice from warm L2
    {
      const int q = tid & 127, kq = tid >> 7;
      const float4* wp = (const float4*)(WF + ((size_t)r*128 + q)*512) + kq*16;
      const float* sp = s_hc + kq*64;
      float ac0=0.f, ac1=0.f, ac2=0.f, ac3=0.f;
      #pragma unroll
      for (int i=0;i<8;++i){
        float4 w0 = wp[2*i], w1 = wp[2*i+1];
        float s0=sp[8*i+0], s1=sp[8*i+1], s2=sp[8*i+2], s3=sp[8*i+3];
        float s4=sp[8*i+4], s5=sp[8*i+5], s6=sp[8*i+6], s7=sp[8*i+7];
        ac0 = fmaf(w0.x,s0,ac0); ac1 = fmaf(w0.y,s1,ac1);
        ac2 = fmaf(w0.z,s2,ac2); ac3 = fmaf(w0.w,s3,ac3);
        ac0 = fmaf(w1.x,s4,ac0); ac1 = fmaf(w1.y,s5,ac1);
        ac2 = fmaf(w1.z,s6,ac2); ac3 = fmaf(w1.w,s7,ac3);
      }
      part[kq*128 + q] = (ac0+ac1)+(ac2+ac3);
    }
    __syncthreads();

    // ---- LSTM pointwise (local 32-wide a-slice); publish h write-through
    if (tid < 32){
      float gi, gf, gg, go;
      if (tf){ gi=xg0; gf=xg1; gg=xg2; go=xg3; }
      else   { gi=xq_s[tid]; gf=xq_s[32+tid]; gg=xq_s[64+tid]; go=xq_s[96+tid]; }
      #pragma unroll
      for (int kq=0;kq<8;++kq){
        const float* pp = part + kq*128;
        gi += pp[tid]; gf += pp[32+tid]; gg += pp[64+tid]; go += pp[96+tid];
      }
      float cn = sigm(gf)*c_s[tid] + sigm(gi)*tanhf(gg);
      float hn = sigm(go)*tanhf(cn);
      c_s[tid] = cn;
      HC[(size_t)m*EE + r*32 + tid] = hn;
      ast(Hx + b*256 + r*32 + tid, hn);
    }
    // ---- barrier A (h published)
    bar_target += 8;
    __syncthreads();
    if (tid == 0){
      sig(mycnt);
      while (poll(mycnt) < bar_target) __builtin_amdgcn_s_sleep(1);
    }
    __syncthreads();

    if (tid < 256) s_hc[256 + tid] = ald(Hx + b*256 + tid);
    __syncthreads();

    // ---- energy partials from LDS kT slice
    {
      const int tq = tid & 127, aq = tid >> 7;
      const float* kp = kTl + (aq*32)*128 + tq;
      const float* hp = s_hc + 256 + aq*32;
      float ac0=0.f, ac1=0.f, ac2=0.f, ac3=0.f;
      #pragma unroll
      for (int i=0;i<8;++i){
        float k0 = kp[(4*i+0)*128], h0 = hp[4*i+0];
        float k1 = kp[(4*i+1)*128], h1 = hp[4*i+1];
        float k2 = kp[(4*i+2)*128], h2 = hp[4*i+2];
        float k3 = kp[(4*i+3)*128], h3 = hp[4*i+3];
        ac0 = fmaf(k0,h0,ac0); ac1 = fmaf(k1,h1,ac1);
        ac2 = fmaf(k2,h2,ac2); ac3 = fmaf(k3,h3,ac3);
      }
      part[aq*128 + tq] = (ac0+ac1)+(ac2+ac3);
    }
    __syncthreads();

    if (tid < 128){
      float ev = NEGI;
      if (tid < tn){
        ev = 0.f;
        #pragma unroll
        for (int q=0;q<8;++q) ev += part[q*128 + tid];
      }
      e_s[tid] = ev;
    }
    __syncthreads();
    if (tid < 64){
      float a = fmaxf(e_s[tid], e_s[64+tid]);
      #pragma unroll
      for (int o=1;o<64;o<<=1) a = fmaxf(a, __shfl_xor(a,o));
      if (tid == 0) red[0] = a;
    }
    __syncthreads();
    const float m_i = red[0];
    if (tid < 128) e_s[tid] = expf(e_s[tid] - m_i);
    __syncthreads();
    if (tid < 64){
      float a = e_s[tid] + e_s[64+tid];
      #pragma unroll
      for (int o=1;o<64;o<<=1) a += __shfl_xor(a,o);
      if (tid == 0) red[1] = a;
    }
    __syncthreads();

    // ---- ctx partials over my t-slice: p × v (warm L2, natural layout)
    {
      const int a = tid & 255, g = tid >> 8;
      float acc = 0.f;
      for (int tt = g; tt < tn; tt += 4){
        acc = fmaf(e_s[tt], v[((size_t)b*TD + t0 + tt)*AA + a], acc);
      }
      cpart[g*256 + a] = acc;
    }
    __syncthreads();
    {
      float* exr = Ex + ((size_t)b*8 + r)*260;
      if (tid < 256){
        float cp = cpart[tid] + cpart[256+tid] + cpart[512+tid] + cpart[768+tid];
        ast(exr + 2 + tid, cp);
      }
      if (tid == 0){ ast(exr + 0, m_i); ast(exr + 1, red[1]); }
    }
    // ---- barrier B (partials published)
    bar_target += 8;
    __syncthreads();
    if (tid == 0){
      sig(mycnt);
      while (poll(mycnt) < bar_target) __builtin_amdgcn_s_sleep(1);
    }
    __syncthreads();

    // ---- combine (fresh pipelined fabric loads; identical fp32 math in every block)
    if (tid < 16){
      int i = tid & 7;
      red[tid] = ald(Ex + ((size_t)b*8 + i)*260 + (tid >> 3));
    }
    __syncthreads();
    if (tid == 0){
      float M = red[0];
      #pragma unroll
      for (int i=1;i<8;++i) M = fmaxf(M, red[i]);
      float S = 0.f;
      #pragma unroll
      for (int i=0;i<8;++i){
        float w = expf(red[i] - M);
        wr_s[i] = w;
        S += w * red[8+i];
      }
      Ssum = S;
    }
    __syncthreads();
    if (tid < 256){
      float* exb = Ex + (size_t)b*8*260 + 2 + tid;
      float c0 = ald(exb + 0*260), c1 = ald(exb + 1*260);
      float c2 = ald(exb + 2*260), c3 = ald(exb + 3*260);
      float c4v= ald(exb + 4*260), c5 = ald(exb + 5*260);
      float c6 = ald(exb + 6*260), c7 = ald(exb + 7*260);
      float cc = wr_s[0]*c0 + wr_s[1]*c1 + wr_s[2]*c2 + wr_s[3]*c3
               + wr_s[4]*c4v + wr_s[5]*c5 + wr_s[6]*c6 + wr_s[7]*c7;
      float cv = cc / Ssum;
      s_hc[tid] = cv;
      if ((tid >> 5) == r) HC[(size_t)m*EE + 256 + tid] = cv;
    }
    __syncthreads();

    const bool need_pred = (t+1 < TO) && !(u[t+1] < ptf);
    if (need_pred){
      const int lane = tid & 63, wvi = tid >> 6;
      float bvv = -3.4e38f; int bii = 0;
      for (int rr=0; rr<8; ++rr){
        int vg = tid*8 + rr;
        float a2 = charb[vg];
        const float* er = embW + (size_t)vg*EE;
        for (int e=0;e<AA;++e) a2 += er[e]*s_hc[256+e];
        for (int e=0;e<AA;++e) a2 += er[AA+e]*s_hc[e];
        if (a2 > bvv){ bvv=a2; bii=vg; }
      }
      #pragma unroll
      for (int o=1;o<64;o<<=1){
        float ov = __shfl_xor(bvv,o); int oi = __shfl_xor(bii,o);
        if (ov > bvv || (ov == bvv && oi < bii)){ bvv=ov; bii=oi; }
      }
      if (lane==0){ rv[wvi]=bvv; ri[wvi]=bii; }
      __syncthreads();
      if (tid==0){
        float fv=rv[0]; int fi=ri[0];
        for (int w2=1;w2<16;++w2){
          if (rv[w2]>fv || (rv[w2]==fv && ri[w2]<fi)){ fv=rv[w2]; fi=ri[w2]; }
        }
        pred_s = fi;
      }
      __syncthreads();
    }
  }
}

// ---- convert HC and embW to bf16 (row-major, K contiguous)
__global__ void kcvt(const float* __restrict__ HC, const float* __restrict__ embW,
                     ushort* __restrict__ HCb, ushort* __restrict__ embB){
  int id = blockIdx.x*blockDim.x + threadIdx.x;
  const int n1 = MM*EE;        // HC elems
  const int n2 = VV*EE;        // emb elems
  for (; id < n1 + n2; id += gridDim.x*blockDim.x){
    if (id < n1){
      HCb[id] = f2bf(HC[id]);
    } else {
      int i2 = id - n1;
      embB[i2] = f2bf(embW[i2]);
    }
  }
}

// ---- logits via MFMA: D[v][m] = emb[v][:]·HC[m][:]; out fp32 (B,V,To)
__global__ __launch_bounds__(256) void klogits_mfma(
    const ushort* __restrict__ HCb, const ushort* __restrict__ embB,
    const float* __restrict__ charb, float* __restrict__ out)
{
  const int mb = blockIdx.x;          // 0..199
  const int vb = blockIdx.y;          // 0..127
  const int wid = threadIdx.x >> 6;
  const int lane = threadIdx.x & 63;
  const int lrow = lane & 15;
  const int lk   = (lane >> 4) * 8;   // k-chunk 0/8/16/24
  const int v0 = vb*64 + wid*16;
  const int m0 = mb*64;

  f32x4 acc0 = {0.f,0.f,0.f,0.f}, acc1 = {0.f,0.f,0.f,0.f};
  f32x4 acc2 = {0.f,0.f,0.f,0.f}, acc3 = {0.f,0.f,0.f,0.f};

  const ushort* ea = embB + (size_t)(v0 + lrow)*EE + lk;
  const ushort* h0 = HCb + (size_t)(m0 +      lrow)*EE + lk;
  const ushort* h1 = HCb + (size_t)(m0 + 16 + lrow)*EE + lk;
  const ushort* h2 = HCb + (size_t)(m0 + 32 + lrow)*EE + lk;
  const ushort* h3 = HCb + (size_t)(m0 + 48 + lrow)*EE + lk;

  #pragma unroll 4
  for (int kc = 0; kc < EE; kc += 32){
    bf16x8 a  = *(const bf16x8*)(ea + kc);
    bf16x8 b0 = *(const bf16x8*)(h0 + kc);
    bf16x8 b1 = *(const bf16x8*)(h1 + kc);
    bf16x8 b2 = *(const bf16x8*)(h2 + kc);
    bf16x8 b3 = *(const bf16x8*)(h3 + kc);
    acc0 = __builtin_amdgcn_mfma_f32_16x16x32_bf16(a, b0, acc0, 0,0,0);
    acc1 = __builtin_amdgcn_mfma_f32_16x16x32_bf16(a, b1, acc1, 0,0,0);
    acc2 = __builtin_amdgcn_mfma_f32_16x16x32_bf16(a, b2, acc2, 0,0,0);
    acc3 = __builtin_amdgcn_mfma_f32_16x16x32_bf16(a, b3, acc3, 0,0,0);
  }

  // D layout: col(m_local)=lane&15, row(v_local)=(lane>>4)*4+reg
  const int vbase = v0 + (lane >> 4)*4;
  #pragma unroll
  for (int j=0; j<4; ++j){
    const f32x4 av = (j==0)?acc0:(j==1)?acc1:(j==2)?acc2:acc3;
    const int m = m0 + j*16 + (lane & 15);
    const int bb = m / TO;
    const int tt = m - bb*TO;
    float* op = out + (size_t)bb*VV*TO + tt;
    #pragma unroll
    for (int i=0;i<4;++i){
      int vg = vbase + i;
      op[(size_t)vg*TO] = av[i] + charb[vg];
    }
  }
}

extern "C" void kernel_launch(void* const* d_in, const int* in_sizes, int n_in,
                              void* d_out, int out_size, void* d_ws, size_t ws_size,
                              hipStream_t stream)
{
  const float* k    = (const float*)d_in[0];
  const float* v    = (const float*)d_in[1];
  const int*   enc  = (const int*)d_in[2];
  const int*   gt   = (const int*)d_in[3];
  const void*  ptf  = d_in[4];
  const float* embW = (const float*)d_in[5];
  const float* Wih  = (const float*)d_in[6];
  const float* Whh  = (const float*)d_in[7];
  const float* bih  = (const float*)d_in[8];
  const float* bhh  = (const float*)d_in[9];
  const float* chb  = (const float*)d_in[10];
  const float* u    = (const float*)d_in[11];
  float* out = (float*)d_out;

  float* ws   = (float*)d_ws;
  uint*  cnt  = (uint*)ws;                        // 1024 u
  float* Hx   = ws + 1024;                        // 32*256
  float* Ex   = Hx + (size_t)BB*256;              // 32*8*260
  float* XG8  = Ex + (size_t)BB*8*260;            // 12800*1024 f (52.4MB)
  float* HC   = XG8 + (size_t)MM*G4;              // 12800*512 f (26.2MB)
  float* WihxT= HC  + (size_t)MM*EE;              // 512*1024 f
  float* WF   = WihxT + (size_t)EE*G4;            // 8*128*512 f (2.1MB)
  float* kT   = WF + (size_t)8*128*512;           // 32*256*896 f (29.4MB)
  ushort* HCb = (ushort*)XG8;                     // aliases XG8 (dead after kseq8): 13.1MB
  ushort* embB= HCb + (size_t)MM*EE;              // +8.4MB (still inside XG8's 52MB)

  hipMemsetAsync(cnt, 0, 1024*sizeof(uint), stream);
  kprep_w  <<<1024, 256, 0, stream>>>(Wih, Whh, WF, WihxT);
  kprep_kT <<<8192, 256, 0, stream>>>(k, kT);
  kxg      <<<dim3(800,4), 256, 0, stream>>>(gt, embW, WihxT, bih, bhh, XG8);
  kseq8    <<<256, 1024, 0, stream>>>(kT, v, enc, ptf, WF, embW, chb, u,
                                      XG8, WihxT, bih, bhh, HC, Hx, Ex, cnt);
  kcvt     <<<4096, 256, 0, stream>>>(HC, embW, HCb, embB);
  klogits_mfma <<<dim3(200,128), 256, 0, stream>>>(HCb, embB, chb, out);
}